// Round 10
// baseline (2843.234 us; speedup 1.0000x reference)
//
#include <hip/hip_runtime.h>
#include <hip/hip_bf16.h>

// Problem constants
#define C1c 256
#define C2c 256
#define NBAT 16
#define HH 56
#define WW 56
#define KS 13
#define PADc 6
#define HP 68                    // 56 + 2*6
#define NPIX (NBAT*HH*WW)        // 50176 = 224 * 224
#define PIXTILES 224             // grid: 224 blocks of 224 pixels
#define PTILE 224                // pixels per block tile
#define KSTEPS2 1352             // 169 * 8 steps of BK=32, order (kh, q, kw)

typedef __bf16 bf16;
typedef bf16 bf16x8 __attribute__((ext_vector_type(8)));
typedef float floatx4 __attribute__((ext_vector_type(4)));

// Workspace layout (bf16):
//   xT : [NBAT*HP*HP][C1]          = 18,939,904 elems (37,879,808 B)
//   wT : [1352][256][32]           = 11,075,584 elems (22,151,168 B)
#define XT_ELEMS ((size_t)NBAT*HP*HP*C1c)
#define WT_ELEMS ((size_t)KSTEPS2*256*32)

// ---------------------------------------------------------------------------
// Pre-pass 1: x (N,C,H,W) fp32 -> xT [(n*68+hp)*68+wp][c1] bf16, padded.
// ---------------------------------------------------------------------------
__global__ __launch_bounds__(256) void xform_x(const float* __restrict__ x,
                                               bf16* __restrict__ xT) {
  __shared__ bf16 tile[56][258];
  const int tid = threadIdx.x;
  const int n = blockIdx.x / HP;
  const int hp = blockIdx.x - n * HP;
  const int ih = hp - PADc;
  const size_t pos_base = (size_t)(n * HP + hp) * HP * C1c;

  if (ih < 0 || ih >= HH) {
#pragma unroll 1
    for (int i = tid; i < HP * 32; i += 256) {
      int wp = i >> 5, g = i & 31;
      *(uint4*)(xT + pos_base + wp * C1c + g * 8) = (uint4){0u, 0u, 0u, 0u};
    }
    return;
  }

  const int wave = tid >> 6, lane = tid & 63;
#pragma unroll 4
  for (int i = 0; i < 64; ++i) {
    int c = i * 4 + wave;                       // covers 0..255 exactly
    if (lane < WW) {
      float v = x[(((size_t)n * C1c + c) * HH + ih) * WW + lane];
      tile[lane][c] = (bf16)v;
    }
  }
  __syncthreads();

#pragma unroll 1
  for (int i = tid; i < HP * 32; i += 256) {
    int wp = i >> 5, g = i & 31;
    int iw = wp - PADc;
    uint4 o;
    if (iw >= 0 && iw < WW) {
      const uint* lp = (const uint*)&tile[iw][g * 8];   // dword-aligned
      o.x = lp[0]; o.y = lp[1]; o.z = lp[2]; o.w = lp[3];
    } else {
      o = (uint4){0u, 0u, 0u, 0u};
    }
    *(uint4*)(xT + pos_base + wp * C1c + g * 8) = o;
  }
}

// ---------------------------------------------------------------------------
// Pre-pass 2: w (C2,C1,13,13) fp32 -> wT [kk][c2][32] bf16
//   kk = (kh*8 + q)*13 + kw,  c1 = q*32 + e   (kw innermost for xT L2 reuse)
//   Layout is fragment-contiguous: a wave's A-frag (16 c2-rows x 32 k) is a
//   1 KB contiguous region — loads straight from L2 into VGPRs.
// ---------------------------------------------------------------------------
__global__ __launch_bounds__(256) void xform_w(const float* __restrict__ w,
                                               bf16* __restrict__ wT) {
  int j = blockIdx.x * 256 + threadIdx.x;   // KSTEPS2*256*4 threads
  int part = j & 3;
  int c2 = (j >> 2) & 255;
  int kk = j >> 10;            // 0..1351
  int kw = kk % 13;
  int t = kk / 13;
  int q = t & 7;
  int kh = t >> 3;
  int c1 = q * 32 + part * 8;
  const float* wp = w + ((size_t)c2 * C1c + c1) * (KS * KS) + kh * KS + kw;
  bf16x8 v;
#pragma unroll
  for (int i = 0; i < 8; i++) v[i] = (bf16)wp[(size_t)i * KS * KS];
  *(bf16x8*)(wT + (size_t)j * 8) = v;
}

// ---------------------------------------------------------------------------
// Main: implicit-GEMM conv + BN + SiLU — BARRIER-FREE, LDS-FREE K-loop.
//   R1..R9 lesson: with shared-LDS staging, the per-step block-wide barrier
//   forces all 8 waves into lockstep (read together, MFMA together) — LDS
//   (1400 cyc) and MFMA (1086 cyc) pipes serialize; every cadence lands at
//   ~2008 cyc/step. R10 removes the shared state entirely:
//   Per step, each wave loads its fragments global->VGPR directly:
//     A: 4 x dwordx4 from wT (1 KB contiguous per frag, L2-hot slab);
//     B: 7 x dwordx4 from xT — per-lane base pos(pix)*256 + kq*8 is a
//        KERNEL-CONSTANT VGPR; only wave-uniform bOn advances (SALU).
//   No ds_read, no gload_lds, no s_barrier: waves are independent; the 2
//   waves/SIMD interleave so one wave's MFMA burst hides the other's L2
//   latency. Loads ordered af,bfr + ni-outer MFMA -> compiler's counted
//   vmcnt staggers the drain.
//   Tile: 256 c2 x 224 px, 8 waves (4M x 2N), wave = 64 c2 x 112 px,
//   acc 4x7 floatx4 = 112 AGPR; ~190 regs total (no spill).
//   Grid = 224 = 8 XCD x 28, swizzle pixt = (orig&7)*28 + (orig>>3).
// ---------------------------------------------------------------------------
__global__ __launch_bounds__(512, 2) void conv_mfma(
    const bf16* __restrict__ xT, const bf16* __restrict__ wT,
    const float* __restrict__ gamma, const float* __restrict__ beta,
    const float* __restrict__ rmean, const float* __restrict__ rvar,
    float* __restrict__ out) {
  __shared__ float sS[256];
  __shared__ float sB[256];

  const int tid = threadIdx.x;
  const int lane = tid & 63;
  const int wave = tid >> 6;           // 0..7
  const int wm = wave >> 1, wn = wave & 1;   // 4M x 2N

  // XCD swizzle over 224 workgroups (224 = 8*28, exact)
  const int orig = blockIdx.x;
  const int pixt = (orig & 7) * 28 + (orig >> 3);
  const int pixbase = pixt * PTILE;

  // BN scale/bias for all 256 c2 rows (only LDS use; only barrier)
  if (tid < 256) {
    float s = gamma[tid] * rsqrtf(rvar[tid] + 1e-5f);
    sS[tid] = s;
    sB[tid] = beta[tid] - rmean[tid] * s;
  }
  __syncthreads();

  // fragment lane constants
  const int mrow = lane & 15;
  const int kq = lane >> 4;                          // k granule (0..3)
  const int aLane = (wm * 64 + mrow) * 32 + kq * 8;  // elems; + mi*512

  // B per-lane kernel-constant bases: pos(pixel)*C1c + kq*8
  int pBe[7];
#pragma unroll
  for (int ni = 0; ni < 7; ni++) {
    int pix = pixbase + wn * 112 + ni * 16 + mrow;
    int n = pix / (HH * WW);
    int rr = pix - n * (HH * WW);
    int oh = rr / WW;
    int ow = rr - oh * WW;
    pBe[ni] = ((n * HP + oh) * HP + ow) * C1c + kq * 8;
  }

  floatx4 acc[4][7];
#pragma unroll
  for (int mi = 0; mi < 4; mi++)
#pragma unroll
    for (int ni = 0; ni < 7; ni++) acc[mi][ni] = (floatx4){0.f, 0.f, 0.f, 0.f};

  // rolling K-step state (wave-uniform; SALU)
  const bf16* aCur = wT;
  int kwc = 0, qc = 0;
  int bOn = 0;                         // (khc*HP + kwc)*C1c + qc*32

#pragma unroll 1
  for (int t = 0; t < KSTEPS2; ++t) {
    bf16x8 af[4], bfr[7];
#pragma unroll
    for (int mi = 0; mi < 4; mi++)
      af[mi] = *(const bf16x8*)(aCur + aLane + mi * 512);
    const bf16* xb = xT + bOn;
#pragma unroll
    for (int ni = 0; ni < 7; ni++)
      bfr[ni] = *(const bf16x8*)(xb + pBe[ni]);

    __builtin_amdgcn_s_setprio(1);
#pragma unroll
    for (int ni = 0; ni < 7; ni++)
#pragma unroll
      for (int mi = 0; mi < 4; mi++)
        acc[mi][ni] = __builtin_amdgcn_mfma_f32_16x16x32_bf16(
            af[mi], bfr[ni], acc[mi][ni], 0, 0, 0);
    __builtin_amdgcn_s_setprio(0);

    // advance (kw innermost, then q, then kh)
    aCur += 8192;
    kwc++; bOn += C1c;
    if (kwc == KS) {
      kwc = 0; qc++; bOn += 32 - KS * C1c;
      if (qc == 8) {
        qc = 0; bOn += HP * C1c - 8 * 32;
      }
    }
  }

  // --- epilogue: BN + SiLU, fp32 NCHW stores ---
  // C/D layout (16x16): col = lane&15 (pixel), row = (lane>>4)*4 + reg (c2)
  const int colL = lane & 15;
  const int quad = lane >> 4;
#pragma unroll
  for (int ni = 0; ni < 7; ni++) {
    int pix = pixbase + wn * 112 + ni * 16 + colL;
    int n = pix / (HH * WW);
    int rr = pix - n * (HH * WW);
    int oh = rr / WW;
    int ow = rr - oh * WW;
    size_t obase = (size_t)n * C2c * (HH * WW) + (size_t)oh * WW + ow;
#pragma unroll
    for (int mi = 0; mi < 4; mi++) {
      int rowb = wm * 64 + mi * 16 + quad * 4;
#pragma unroll
      for (int r = 0; r < 4; r++) {
        int rowl = rowb + r;
        float v = acc[mi][ni][r];
        v = v * sS[rowl] + sB[rowl];
        float o = v / (1.f + __expf(-v));
        out[obase + (size_t)rowl * (HH * WW)] = o;
      }
    }
  }
}

// ---------------------------------------------------------------------------
extern "C" void kernel_launch(void* const* d_in, const int* in_sizes, int n_in,
                              void* d_out, int out_size, void* d_ws, size_t ws_size,
                              hipStream_t stream) {
  const float* x     = (const float*)d_in[0];
  const float* w     = (const float*)d_in[1];
  const float* gamma = (const float*)d_in[2];
  const float* beta  = (const float*)d_in[3];
  const float* rmean = (const float*)d_in[4];
  const float* rvar  = (const float*)d_in[5];
  float* out = (float*)d_out;

  bf16* xT = (bf16*)d_ws;
  bf16* wT = xT + XT_ELEMS;

  if (ws_size < (XT_ELEMS + WT_ELEMS) * sizeof(bf16)) return;  // need ~57.3 MiB

  xform_x<<<NBAT * HP, 256, 0, stream>>>(x, xT);
  xform_w<<<(KSTEPS2 * 256 * 4) / 256, 256, 0, stream>>>(w, wT);
  conv_mfma<<<PIXTILES, 512, 0, stream>>>(xT, wT, gamma, beta, rmean, rvar, out);
}